// Round 2
// baseline (1082.499 us; speedup 1.0000x reference)
//
#include <hip/hip_runtime.h>
#include <stdint.h>

// Top-k (k=10% of N) by value, scatter-back, zeros elsewhere.
// Single full read pass for selection:
//   sample 64k elements -> predict k-quantile in sortable-u32 space
//   main pass: count(u above window) exactly + exact per-value histogram
//              inside a 2^22-wide window around the prediction (16 MB ws)
//   hierarchical scan -> exact 32-bit threshold t_u + tie count
// Early-exit fallback (16+16 bit radix) guarantees correctness if the
// window misses (k_rem out of range). Then one dense compare/scatter pass
// with fused stable tie-fix (smallest indices win, matching lax.top_k).

#define EQ_CAP 65536

#define SC_WLO   0
#define SC_K     1
#define SC_TU    2
#define SC_NEED  3
#define SC_EQN   4
#define SC_OK    5
#define SC_ABOVE 6
#define SC_DONE1 7
#define SC_DONE2 8
#define SC_FBHI  9
#define SC_FBKR  10

__device__ __forceinline__ unsigned int f2u(float x) {
    unsigned int b = __float_as_uint(x);
    return (b & 0x80000000u) ? ~b : (b | 0x80000000u);
}
__device__ __forceinline__ float u2f(unsigned int u) {
    return __uint_as_float((u & 0x80000000u) ? (u & 0x7FFFFFFFu) : ~u);
}

__device__ __forceinline__ unsigned int block_exscan256(unsigned int v,
                                                        unsigned int* lds,
                                                        int tid)
{
    lds[tid] = v;
    __syncthreads();
    for (int off = 1; off < 256; off <<= 1) {
        unsigned int t = (tid >= off) ? lds[tid - off] : 0u;
        __syncthreads();
        lds[tid] += t;
        __syncthreads();
    }
    return lds[tid] - v;
}

// ---------------- sample + init ----------------
__global__ void __launch_bounds__(1024)
sample_kernel(const float* __restrict__ x, long long N, unsigned int k,
              unsigned int* __restrict__ sc, unsigned int wbits)
{
    __shared__ unsigned int lh[2048];
    __shared__ unsigned int s_u;
    int tid = threadIdx.x;
    for (int i = tid; i < 2048; i += 1024) lh[i] = 0u;
    __syncthreads();
    const int NS = 65536;
    long long stride = N / NS; if (stride < 1) stride = 1;
    for (int it = 0; it < NS / 1024; ++it) {
        long long idx = (long long)(tid + it * 1024) * stride;
        if (idx < N) {
            unsigned int u = f2u(x[idx]);
            atomicAdd(&lh[u >> 21], 1u);
        }
    }
    __syncthreads();
    if (tid < 64) {
        unsigned int part = 0u;
        for (int j = 0; j < 32; ++j) part += lh[2047 - (tid * 32 + j)];
        unsigned int incl = part;
        for (int o = 1; o < 64; o <<= 1) {
            unsigned int t = __shfl_up(incl, o, 64);
            if (tid >= o) incl += t;
        }
        unsigned int ex = incl - part;
        unsigned int ks = (unsigned int)((double)NS * (double)k / (double)N);
        if (ks < 1u) ks = 1u;
        unsigned int cum = ex;
        for (int j = 0; j < 32; ++j) {
            int bin = 2047 - (tid * 32 + j);
            unsigned int c = lh[bin];
            if (cum < ks && cum + c >= ks)
                s_u = ((unsigned int)bin << 21) | (1u << 20);
            cum += c;
        }
    }
    __syncthreads();
    if (tid == 0) {
        unsigned int wsize = 1u << wbits;
        unsigned int half = wsize >> 1;
        unsigned int uhat = s_u;
        unsigned int wlo = (uhat > half) ? (uhat - half) : 0u;
        unsigned int wlomax = (unsigned int)(0u - wsize);
        if (wlo > wlomax) wlo = wlomax;
        sc[SC_WLO] = wlo;  sc[SC_K] = k;
        sc[SC_TU] = 0u;    sc[SC_NEED] = 0u;  sc[SC_EQN] = 0u;
        sc[SC_OK] = 0u;    sc[SC_ABOVE] = 0u;
        sc[SC_DONE1] = 0u; sc[SC_DONE2] = 0u;
        sc[SC_FBHI] = 0u;  sc[SC_FBKR] = 0u;
    }
}

// ---------------- main full pass ----------------
__global__ void __launch_bounds__(256)
main_kernel(const float* __restrict__ x, int n4, long long N,
            unsigned int* __restrict__ fine,
            unsigned int* __restrict__ fbz,   // 131072 u32 (fbA|fbB) to zero
            unsigned int* __restrict__ sc, unsigned int wbits)
{
    int tid = threadIdx.x;
    int g = blockIdx.x * blockDim.x + tid;
    if (g < 131072) fbz[g] = 0u;
    unsigned int wlo = sc[SC_WLO];
    unsigned int whiM1 = wlo + (1u << wbits) - 1u;
    const float4* x4 = (const float4*)x;
    int stride = gridDim.x * blockDim.x;
    unsigned int above = 0u;
    for (int i = g; i < n4; i += stride) {
        float4 v = x4[i];
        unsigned int u;
        u = f2u(v.x); if (u > whiM1) ++above; else if (u >= wlo) atomicAdd(&fine[u - wlo], 1u);
        u = f2u(v.y); if (u > whiM1) ++above; else if (u >= wlo) atomicAdd(&fine[u - wlo], 1u);
        u = f2u(v.z); if (u > whiM1) ++above; else if (u >= wlo) atomicAdd(&fine[u - wlo], 1u);
        u = f2u(v.w); if (u > whiM1) ++above; else if (u >= wlo) atomicAdd(&fine[u - wlo], 1u);
    }
    long long t0 = (long long)n4 * 4;
    if (blockIdx.x == 0 && tid < (int)(N - t0)) {
        unsigned int u = f2u(x[t0 + tid]);
        if (u > whiM1) ++above; else if (u >= wlo) atomicAdd(&fine[u - wlo], 1u);
    }
    for (int o = 32; o; o >>= 1) above += __shfl_down(above, o, 64);
    if ((tid & 63) == 0 && above) atomicAdd(&sc[SC_ABOVE], above);
}

// ---------------- hierarchical scan of fine hist (chunksum + last-block final) ---
__global__ void __launch_bounds__(256)
scan_fine_kernel(const unsigned int* __restrict__ fine,
                 unsigned int* __restrict__ chunk_sums,
                 unsigned int* __restrict__ sc)
{
    __shared__ unsigned int lds[256];
    __shared__ unsigned int sh[4];      // 0:is_last 1:chunk 2:krem2
    __shared__ unsigned int s_total;
    int tid = threadIdx.x;
    int nchunk = gridDim.x;
    const unsigned int* base = fine + (size_t)blockIdx.x * 1024;
    unsigned int s = 0u;
    for (int i = tid; i < 1024; i += 256) s += base[i];
    lds[tid] = s;
    __syncthreads();
    for (int o = 128; o; o >>= 1) { if (tid < o) lds[tid] += lds[tid + o]; __syncthreads(); }
    if (tid == 0) chunk_sums[blockIdx.x] = lds[0];
    __threadfence();
    if (tid == 0) {
        unsigned int old = atomicAdd(&sc[SC_DONE1], 1u);
        sh[0] = (old == (unsigned int)(nchunk - 1)) ? 1u : 0u;
    }
    __syncthreads();
    if (!sh[0]) return;
    __threadfence();
    // ---- last block: final descending scan ----
    unsigned int k = sc[SC_K];
    unsigned int above = sc[SC_ABOVE];
    int seg = nchunk >> 8;
    unsigned int part = 0u;
    for (int j = 0; j < seg; ++j) part += chunk_sums[nchunk - 1 - (tid * seg + j)];
    unsigned int ex = block_exscan256(part, lds, tid);
    if (tid == 255) s_total = ex + part;
    __syncthreads();
    unsigned int total = s_total;
    unsigned int valid = (above < k) && ((k - above) <= total);
    if (tid == 0) sc[SC_OK] = valid;
    if (!valid) return;
    unsigned int krem = k - above;
    unsigned int cum = ex;
    for (int j = 0; j < seg; ++j) {
        int c = nchunk - 1 - (tid * seg + j);
        unsigned int cc = chunk_sums[c];
        if (cum < krem && cum + cc >= krem) { sh[1] = (unsigned int)c; sh[2] = krem - cum; }
        cum += cc;
    }
    __syncthreads();
    unsigned int C = sh[1], krem2 = sh[2];
    unsigned int loc[4]; unsigned int p2 = 0u;
    for (int j = 0; j < 4; ++j) {
        unsigned int v = fine[(size_t)C * 1024 + (1023 - (tid * 4 + j))];
        loc[j] = v; p2 += v;
    }
    __syncthreads();
    unsigned int ex2 = block_exscan256(p2, lds, tid);
    unsigned int cum2 = ex2;
    for (int j = 0; j < 4; ++j) {
        int bin = 1023 - (tid * 4 + j);
        unsigned int cc = loc[j];
        if (cum2 < krem2 && cum2 + cc >= krem2) {
            sc[SC_TU] = sc[SC_WLO] + C * 1024u + (unsigned int)bin;
            sc[SC_NEED] = krem2 - cum2;
        }
        cum2 += cc;
    }
}

// ---------------- fallback (early-exit when SC_OK) ----------------
__global__ void __launch_bounds__(256)
fb_hist_kernel(const float* __restrict__ x, int n4, long long N,
               unsigned int* __restrict__ hist,
               const unsigned int* __restrict__ sc, int lowpass)
{
    if (sc[SC_OK]) return;
    unsigned int pref = lowpass ? sc[SC_FBHI] : 0u;
    const float4* x4 = (const float4*)x;
    int stride = gridDim.x * blockDim.x;
    for (int i = blockIdx.x * blockDim.x + threadIdx.x; i < n4; i += stride) {
        float4 v = x4[i];
        unsigned int u;
        #define FB_ONE(c) u = f2u(c); \
            if (!lowpass) atomicAdd(&hist[u >> 16], 1u); \
            else if ((u >> 16) == pref) atomicAdd(&hist[u & 0xFFFFu], 1u);
        FB_ONE(v.x) FB_ONE(v.y) FB_ONE(v.z) FB_ONE(v.w)
        #undef FB_ONE
    }
    long long t0 = (long long)n4 * 4;
    if (blockIdx.x == 0 && threadIdx.x < (int)(N - t0)) {
        unsigned int u = f2u(x[t0 + threadIdx.x]);
        if (!lowpass) atomicAdd(&hist[u >> 16], 1u);
        else if ((u >> 16) == pref) atomicAdd(&hist[u & 0xFFFFu], 1u);
    }
}

__global__ void __launch_bounds__(256)
fb_scan_kernel(const unsigned int* __restrict__ hist,
               unsigned int* __restrict__ sc, int lowpass)
{
    if (sc[SC_OK]) return;
    __shared__ unsigned int lds[256];
    int tid = threadIdx.x;
    unsigned int krem = lowpass ? sc[SC_FBKR] : sc[SC_K];
    unsigned int part = 0u;
    for (int j = 0; j < 256; ++j) part += hist[65535 - (tid * 256 + j)];
    unsigned int ex = block_exscan256(part, lds, tid);
    unsigned int cum = ex;
    for (int j = 0; j < 256; ++j) {
        int bin = 65535 - (tid * 256 + j);
        unsigned int cc = hist[bin];
        if (cum < krem && cum + cc >= krem) {
            if (!lowpass) { sc[SC_FBHI] = (unsigned int)bin; sc[SC_FBKR] = krem - cum; }
            else { sc[SC_TU] = (sc[SC_FBHI] << 16) | (unsigned int)bin; sc[SC_NEED] = krem - cum; }
        }
        cum += cc;
    }
}

// ---------------- scatter + fused stable tie-fix ----------------
__global__ void __launch_bounds__(256)
scatter_kernel(const float* __restrict__ x, int n4, long long N,
               float* __restrict__ out, unsigned int* __restrict__ sc,
               unsigned int* __restrict__ eq_list, int cap)
{
    __shared__ unsigned int s_last;
    int tid = threadIdx.x;
    unsigned int tu = sc[SC_TU];
    const float4* x4 = (const float4*)x;
    float4* o4 = (float4*)out;
    int stride = gridDim.x * blockDim.x;
    for (int i = blockIdx.x * blockDim.x + tid; i < n4; i += stride) {
        float4 v = x4[i];
        unsigned int u0 = f2u(v.x), u1 = f2u(v.y), u2 = f2u(v.z), u3 = f2u(v.w);
        float4 o;
        o.x = (u0 > tu) ? v.x : 0.0f;
        o.y = (u1 > tu) ? v.y : 0.0f;
        o.z = (u2 > tu) ? v.z : 0.0f;
        o.w = (u3 > tu) ? v.w : 0.0f;
        if (u0 == tu || u1 == tu || u2 == tu || u3 == tu) {
            unsigned int b = (unsigned int)i * 4u;
            if (u0 == tu) { unsigned int p = atomicAdd(&sc[SC_EQN], 1u); if (p < (unsigned int)cap) eq_list[p] = b + 0u; }
            if (u1 == tu) { unsigned int p = atomicAdd(&sc[SC_EQN], 1u); if (p < (unsigned int)cap) eq_list[p] = b + 1u; }
            if (u2 == tu) { unsigned int p = atomicAdd(&sc[SC_EQN], 1u); if (p < (unsigned int)cap) eq_list[p] = b + 2u; }
            if (u3 == tu) { unsigned int p = atomicAdd(&sc[SC_EQN], 1u); if (p < (unsigned int)cap) eq_list[p] = b + 3u; }
        }
        o4[i] = o;
    }
    long long t0 = (long long)n4 * 4;
    if (blockIdx.x == 0 && tid < (int)(N - t0)) {
        long long idx = t0 + tid;
        float v = x[idx];
        unsigned int u = f2u(v);
        out[idx] = (u > tu) ? v : 0.0f;
        if (u == tu) { unsigned int p = atomicAdd(&sc[SC_EQN], 1u); if (p < (unsigned int)cap) eq_list[p] = (unsigned int)idx; }
    }
    __threadfence();
    __syncthreads();
    if (tid == 0) {
        unsigned int old = atomicAdd(&sc[SC_DONE2], 1u);
        s_last = (old == gridDim.x - 1u) ? 1u : 0u;
    }
    __syncthreads();
    if (!s_last) return;
    __threadfence();
    unsigned int m = sc[SC_EQN]; if (m > (unsigned int)cap) m = (unsigned int)cap;
    unsigned int need = sc[SC_NEED];
    float f = u2f(tu);
    for (unsigned int j = tid; j < m; j += 256) {
        unsigned int idx = eq_list[j];
        unsigned int cnt = 0u;
        for (unsigned int l = 0; l < m; ++l) cnt += (eq_list[l] < idx) ? 1u : 0u;
        if (cnt < need) out[idx] = f;
    }
}

extern "C" void kernel_launch(void* const* d_in, const int* in_sizes, int n_in,
                              void* d_out, int out_size, void* d_ws, size_t ws_size,
                              hipStream_t stream) {
    const float* x = (const float*)d_in[0];
    float* out = (float*)d_out;
    long long N = (long long)in_sizes[0];
    int n4 = (int)(N >> 2);
    unsigned int k = (unsigned int)((double)N * 0.1);
    if (k == 0u) k = 1u;

    unsigned int wbits = 22;
    if (ws_size < (1u << 20) + ((size_t)4u << 22)) wbits = 19;  // tight ws fallback

    uint8_t* w = (uint8_t*)d_ws;
    unsigned int* sc         = (unsigned int*)w;                       // 256 B
    unsigned int* chunk_sums = (unsigned int*)(w + 1024);              // 16 KB max
    unsigned int* fbz        = (unsigned int*)(w + 32768);             // 512 KB (fbA|fbB)
    unsigned int* fbA        = fbz;
    unsigned int* fbB        = fbz + 65536;
    unsigned int* eq_list    = (unsigned int*)(w + 32768 + 524288);    // 256 KB
    unsigned int* fine       = (unsigned int*)(w + (1u << 20));        // 16 MB (wbits=22)

    int nchunk = 1 << (wbits - 10);

    hipMemsetAsync(fine, 0, ((size_t)4u << wbits), stream);
    sample_kernel<<<1, 1024, 0, stream>>>(x, N, k, sc, wbits);
    main_kernel<<<2048, 256, 0, stream>>>(x, n4, N, fine, fbz, sc, wbits);
    scan_fine_kernel<<<nchunk, 256, 0, stream>>>(fine, chunk_sums, sc);
    fb_hist_kernel<<<1024, 256, 0, stream>>>(x, n4, N, fbA, sc, 0);
    fb_scan_kernel<<<1, 256, 0, stream>>>(fbA, sc, 0);
    fb_hist_kernel<<<1024, 256, 0, stream>>>(x, n4, N, fbB, sc, 1);
    fb_scan_kernel<<<1, 256, 0, stream>>>(fbB, sc, 1);
    scatter_kernel<<<2048, 256, 0, stream>>>(x, n4, N, out, sc, eq_list, EQ_CAP);
}

// Round 3
// 377.327 us; speedup vs baseline: 2.8689x; 2.8689x over previous
//
#include <hip/hip_runtime.h>
#include <stdint.h>

// Top-k (k=10% of N) by value over flat fp32; scatter values back, zeros
// elsewhere. One full selection read pass + one compare/scatter pass.
//   stage 1: two-stage 64K-sample estimate of the k-quantile in sortable-u32
//            space (multi-block, non-returning atomics only)
//   stage 2: full pass counts u>window exactly + exact per-value histogram
//            inside a 2^20-wide window (4 MB ws)
//   stage 3: chunksum + single-block scan -> exact threshold t_u + tie count
//   fallback: exact 16+16-bit radix (2 extra passes) if window missed
//   stage 4: dense compare/scatter; stable tie-fix (smallest indices win).
// NO returning same-address cross-block atomics anywhere (R2 lesson: 4096 of
// them serialized at ~78ns each = 319us stall).

#define EQ_CAP 65536

#define SC_WLO   0
#define SC_ABOVE 1
#define SC_TU    2
#define SC_NEED  3
#define SC_EQN   4
#define SC_OK    5
#define SC_FBHI  6
#define SC_FBKR  7
#define SC_SB    8
#define SC_SKR   9

__device__ __forceinline__ unsigned int f2u(float x) {
    unsigned int b = __float_as_uint(x);
    return (b & 0x80000000u) ? ~b : (b | 0x80000000u);
}
__device__ __forceinline__ float u2f(unsigned int u) {
    return __uint_as_float((u & 0x80000000u) ? (u & 0x7FFFFFFFu) : ~u);
}

__device__ __forceinline__ unsigned int block_exscan256(unsigned int v,
                                                        unsigned int* lds,
                                                        int tid)
{
    lds[tid] = v;
    __syncthreads();
    for (int off = 1; off < 256; off <<= 1) {
        unsigned int t = (tid >= off) ? lds[tid - off] : 0u;
        __syncthreads();
        lds[tid] += t;
        __syncthreads();
    }
    return lds[tid] - v;
}

// ---------------- sampling (two-stage, multi-block) ----------------
__global__ void __launch_bounds__(256)
sampleA_kernel(const float* __restrict__ x, long long N, long long sstride,
               unsigned int NS, unsigned int* __restrict__ sampA)
{
    unsigned int g = blockIdx.x * 256u + threadIdx.x;
    if (g < NS) {
        long long idx = (long long)g * sstride;
        if (idx < N) {
            unsigned int u = f2u(x[idx]);
            atomicAdd(&sampA[u >> 21], 1u);   // non-returning
        }
    }
}

__global__ void __launch_bounds__(256)
scanA_kernel(const unsigned int* __restrict__ sampA,
             unsigned int* __restrict__ sc, unsigned int ks)
{
    __shared__ unsigned int lds[256];
    int tid = threadIdx.x;
    unsigned int loc[8]; unsigned int part = 0u;
    for (int j = 0; j < 8; ++j) {
        unsigned int v = sampA[2047 - (tid * 8 + j)];
        loc[j] = v; part += v;
    }
    unsigned int cum = block_exscan256(part, lds, tid);
    for (int j = 0; j < 8; ++j) {
        int bin = 2047 - (tid * 8 + j);
        unsigned int c = loc[j];
        if (cum < ks && cum + c >= ks) { sc[SC_SB] = (unsigned int)bin; sc[SC_SKR] = ks - cum; }
        cum += c;
    }
}

__global__ void __launch_bounds__(256)
sampleB_kernel(const float* __restrict__ x, long long N, long long sstride,
               unsigned int NS, unsigned int* __restrict__ sampB,
               const unsigned int* __restrict__ sc)
{
    unsigned int B = sc[SC_SB];
    unsigned int g = blockIdx.x * 256u + threadIdx.x;
    if (g < NS) {
        long long idx = (long long)g * sstride;
        if (idx < N) {
            unsigned int u = f2u(x[idx]);
            if ((u >> 21) == B) atomicAdd(&sampB[(u >> 10) & 2047u], 1u);
        }
    }
}

__global__ void __launch_bounds__(256)
scanB_kernel(const unsigned int* __restrict__ sampB,
             unsigned int* __restrict__ sc, unsigned int wbits)
{
    __shared__ unsigned int lds[256];
    int tid = threadIdx.x;
    unsigned int krem = sc[SC_SKR];
    unsigned int B = sc[SC_SB];
    unsigned int loc[8]; unsigned int part = 0u;
    for (int j = 0; j < 8; ++j) {
        unsigned int v = sampB[2047 - (tid * 8 + j)];
        loc[j] = v; part += v;
    }
    unsigned int cum = block_exscan256(part, lds, tid);
    for (int j = 0; j < 8; ++j) {
        int bin = 2047 - (tid * 8 + j);
        unsigned int c = loc[j];
        if (cum < krem && cum + c >= krem) {
            unsigned int uhat = (B << 21) | ((unsigned int)bin << 10) | (1u << 9);
            unsigned int wsize = 1u << wbits;
            unsigned int half = wsize >> 1;
            unsigned int wlo = (uhat > half) ? (uhat - half) : 0u;
            unsigned int wlomax = (unsigned int)(0u - wsize);
            if (wlo > wlomax) wlo = wlomax;
            sc[SC_WLO] = wlo;
        }
        cum += c;
    }
}

// ---------------- main full selection pass ----------------
__global__ void __launch_bounds__(256)
main_kernel(const float* __restrict__ x, int n4, long long N,
            unsigned int* __restrict__ fine,
            unsigned int* __restrict__ fbz,   // 131072 u32 to zero (fbA|fbB)
            unsigned int* __restrict__ sc, unsigned int wbits)
{
    __shared__ unsigned int wsum[4];
    int tid = threadIdx.x;
    int g = blockIdx.x * blockDim.x + tid;
    if (g < 131072) fbz[g] = 0u;
    unsigned int wlo = sc[SC_WLO];
    unsigned int whiM1 = wlo + (1u << wbits) - 1u;
    const float4* x4 = (const float4*)x;
    int stride = gridDim.x * blockDim.x;
    unsigned int above = 0u;
    for (int i = g; i < n4; i += stride) {
        float4 v = x4[i];
        unsigned int u;
        u = f2u(v.x); if (u > whiM1) ++above; else if (u >= wlo) atomicAdd(&fine[u - wlo], 1u);
        u = f2u(v.y); if (u > whiM1) ++above; else if (u >= wlo) atomicAdd(&fine[u - wlo], 1u);
        u = f2u(v.z); if (u > whiM1) ++above; else if (u >= wlo) atomicAdd(&fine[u - wlo], 1u);
        u = f2u(v.w); if (u > whiM1) ++above; else if (u >= wlo) atomicAdd(&fine[u - wlo], 1u);
    }
    long long t0 = (long long)n4 * 4;
    if (blockIdx.x == 0 && tid < (int)(N - t0)) {
        unsigned int u = f2u(x[t0 + tid]);
        if (u > whiM1) ++above; else if (u >= wlo) atomicAdd(&fine[u - wlo], 1u);
    }
    for (int o = 32; o; o >>= 1) above += __shfl_down(above, o, 64);
    if ((tid & 63) == 0) wsum[tid >> 6] = above;
    __syncthreads();
    if (tid == 0) {
        unsigned int s = wsum[0] + wsum[1] + wsum[2] + wsum[3];
        if (s) atomicAdd(&sc[SC_ABOVE], s);   // non-returning, 1 per block
    }
}

// ---------------- chunksum (no completion atomic) ----------------
__global__ void __launch_bounds__(256)
chunksum_kernel(const unsigned int* __restrict__ fine,
                unsigned int* __restrict__ chunk_sums)
{
    __shared__ unsigned int p[256];
    int tid = threadIdx.x;
    const unsigned int* base = fine + (size_t)blockIdx.x * 1024;
    unsigned int s = 0u;
    for (int i = tid; i < 1024; i += 256) s += base[i];
    p[tid] = s;
    __syncthreads();
    for (int o = 128; o; o >>= 1) { if (tid < o) p[tid] += p[tid + o]; __syncthreads(); }
    if (tid == 0) chunk_sums[blockIdx.x] = p[0];
}

// ---------------- final single-block scan ----------------
__global__ void __launch_bounds__(256)
final_kernel(const unsigned int* __restrict__ fine,
             const unsigned int* __restrict__ chunk_sums,
             unsigned int* __restrict__ sc, unsigned int k, int nchunk)
{
    __shared__ unsigned int lds[256];
    __shared__ unsigned int sh[3];   // chunk, krem2
    __shared__ unsigned int s_total;
    int tid = threadIdx.x;
    unsigned int above = sc[SC_ABOVE];
    int seg = nchunk >> 8;
    unsigned int part = 0u;
    for (int j = 0; j < seg; ++j) part += chunk_sums[nchunk - 1 - (tid * seg + j)];
    unsigned int ex = block_exscan256(part, lds, tid);
    if (tid == 255) s_total = ex + part;
    __syncthreads();
    unsigned int total = s_total;
    unsigned int valid = (above < k) && ((k - above) <= total);
    if (tid == 0) sc[SC_OK] = valid;
    if (!valid) return;
    unsigned int krem = k - above;
    unsigned int cum = ex;
    for (int j = 0; j < seg; ++j) {
        int c = nchunk - 1 - (tid * seg + j);
        unsigned int cc = chunk_sums[c];
        if (cum < krem && cum + cc >= krem) { sh[0] = (unsigned int)c; sh[1] = krem - cum; }
        cum += cc;
    }
    __syncthreads();
    unsigned int C = sh[0], krem2 = sh[1];
    unsigned int loc[4]; unsigned int p2 = 0u;
    for (int j = 0; j < 4; ++j) {
        unsigned int v = fine[(size_t)C * 1024 + (1023 - (tid * 4 + j))];
        loc[j] = v; p2 += v;
    }
    __syncthreads();
    unsigned int ex2 = block_exscan256(p2, lds, tid);
    unsigned int cum2 = ex2;
    for (int j = 0; j < 4; ++j) {
        int bin = 1023 - (tid * 4 + j);
        unsigned int cc = loc[j];
        if (cum2 < krem2 && cum2 + cc >= krem2) {
            sc[SC_TU] = sc[SC_WLO] + C * 1024u + (unsigned int)bin;
            sc[SC_NEED] = krem2 - cum2;
        }
        cum2 += cc;
    }
}

// ---------------- exact fallback (early-exit when SC_OK) ----------------
__global__ void __launch_bounds__(256)
fb_hist_kernel(const float* __restrict__ x, int n4, long long N,
               unsigned int* __restrict__ hist,
               const unsigned int* __restrict__ sc, int lowpass)
{
    if (sc[SC_OK]) return;
    unsigned int pref = lowpass ? sc[SC_FBHI] : 0u;
    const float4* x4 = (const float4*)x;
    int stride = gridDim.x * blockDim.x;
    for (int i = blockIdx.x * blockDim.x + threadIdx.x; i < n4; i += stride) {
        float4 v = x4[i];
        unsigned int u;
        #define FB_ONE(c) u = f2u(c); \
            if (!lowpass) atomicAdd(&hist[u >> 16], 1u); \
            else if ((u >> 16) == pref) atomicAdd(&hist[u & 0xFFFFu], 1u);
        FB_ONE(v.x) FB_ONE(v.y) FB_ONE(v.z) FB_ONE(v.w)
        #undef FB_ONE
    }
    long long t0 = (long long)n4 * 4;
    if (blockIdx.x == 0 && threadIdx.x < (int)(N - t0)) {
        unsigned int u = f2u(x[t0 + threadIdx.x]);
        if (!lowpass) atomicAdd(&hist[u >> 16], 1u);
        else if ((u >> 16) == pref) atomicAdd(&hist[u & 0xFFFFu], 1u);
    }
}

__global__ void __launch_bounds__(256)
fb_scan_kernel(const unsigned int* __restrict__ hist,
               unsigned int* __restrict__ sc, int lowpass, unsigned int k)
{
    if (sc[SC_OK]) return;
    __shared__ unsigned int lds[256];
    int tid = threadIdx.x;
    unsigned int krem = lowpass ? sc[SC_FBKR] : k;
    unsigned int part = 0u;
    for (int j = 0; j < 256; ++j) part += hist[65535 - (tid * 256 + j)];
    unsigned int ex = block_exscan256(part, lds, tid);
    unsigned int cum = ex;
    for (int j = 0; j < 256; ++j) {
        int bin = 65535 - (tid * 256 + j);
        unsigned int cc = hist[bin];
        if (cum < krem && cum + cc >= krem) {
            if (!lowpass) { sc[SC_FBHI] = (unsigned int)bin; sc[SC_FBKR] = krem - cum; }
            else { sc[SC_TU] = (sc[SC_FBHI] << 16) | (unsigned int)bin; sc[SC_NEED] = krem - cum; }
        }
        cum += cc;
    }
}

// ---------------- scatter ----------------
__global__ void __launch_bounds__(256)
scatter_kernel(const float* __restrict__ x, int n4, long long N,
               float* __restrict__ out, unsigned int* __restrict__ sc,
               unsigned int* __restrict__ eq_list, int cap)
{
    int tid = threadIdx.x;
    unsigned int tu = sc[SC_TU];
    const float4* x4 = (const float4*)x;
    float4* o4 = (float4*)out;
    int stride = gridDim.x * blockDim.x;
    for (int i = blockIdx.x * blockDim.x + tid; i < n4; i += stride) {
        float4 v = x4[i];
        unsigned int u0 = f2u(v.x), u1 = f2u(v.y), u2 = f2u(v.z), u3 = f2u(v.w);
        float4 o;
        o.x = (u0 > tu) ? v.x : 0.0f;
        o.y = (u1 > tu) ? v.y : 0.0f;
        o.z = (u2 > tu) ? v.z : 0.0f;
        o.w = (u3 > tu) ? v.w : 0.0f;
        if (u0 == tu || u1 == tu || u2 == tu || u3 == tu) {   // ~a few per launch
            unsigned int b = (unsigned int)i * 4u;
            if (u0 == tu) { unsigned int p = atomicAdd(&sc[SC_EQN], 1u); if (p < (unsigned int)cap) eq_list[p] = b + 0u; }
            if (u1 == tu) { unsigned int p = atomicAdd(&sc[SC_EQN], 1u); if (p < (unsigned int)cap) eq_list[p] = b + 1u; }
            if (u2 == tu) { unsigned int p = atomicAdd(&sc[SC_EQN], 1u); if (p < (unsigned int)cap) eq_list[p] = b + 2u; }
            if (u3 == tu) { unsigned int p = atomicAdd(&sc[SC_EQN], 1u); if (p < (unsigned int)cap) eq_list[p] = b + 3u; }
        }
        o4[i] = o;
    }
    long long t0 = (long long)n4 * 4;
    if (blockIdx.x == 0 && tid < (int)(N - t0)) {
        long long idx = t0 + tid;
        float v = x[idx];
        unsigned int u = f2u(v);
        out[idx] = (u > tu) ? v : 0.0f;
        if (u == tu) { unsigned int p = atomicAdd(&sc[SC_EQN], 1u); if (p < (unsigned int)cap) eq_list[p] = (unsigned int)idx; }
    }
}

// stable tie-break: among ==t_u elements, the SC_NEED smallest indices win
__global__ void __launch_bounds__(256)
eqfix_kernel(float* __restrict__ out, const unsigned int* __restrict__ sc,
             const unsigned int* __restrict__ eq_list, int cap)
{
    unsigned int m = sc[SC_EQN]; if (m > (unsigned int)cap) m = (unsigned int)cap;
    unsigned int need = sc[SC_NEED];
    unsigned int tu = sc[SC_TU];
    float f = u2f(tu);
    for (unsigned int j = threadIdx.x; j < m; j += blockDim.x) {
        unsigned int idx = eq_list[j];
        unsigned int cnt = 0u;
        for (unsigned int l = 0; l < m; ++l) cnt += (eq_list[l] < idx) ? 1u : 0u;
        if (cnt < need) out[idx] = f;
    }
}

extern "C" void kernel_launch(void* const* d_in, const int* in_sizes, int n_in,
                              void* d_out, int out_size, void* d_ws, size_t ws_size,
                              hipStream_t stream) {
    const float* x = (const float*)d_in[0];
    float* out = (float*)d_out;
    long long N = (long long)in_sizes[0];
    int n4 = (int)(N >> 2);
    unsigned int k = (unsigned int)((double)N * 0.1);
    if (k == 0u) k = 1u;

    unsigned int NS = (N < 65536) ? (unsigned int)N : 65536u;
    long long sstride = N / NS; if (sstride < 1) sstride = 1;
    unsigned int ks = (unsigned int)((double)NS * (double)k / (double)N);
    if (ks < 1u) ks = 1u; if (ks > NS) ks = NS;

    unsigned int wbits = 20;
    if (ws_size < (1u << 20) + ((size_t)4u << 20)) wbits = 18;
    int nchunk = 1 << (wbits - 10);

    uint8_t* w = (uint8_t*)d_ws;
    unsigned int* sc         = (unsigned int*)w;                  // 1 KB
    unsigned int* sampA      = (unsigned int*)(w + 1024);         // 8 KB
    unsigned int* sampB      = (unsigned int*)(w + 9216);         // 8 KB
    unsigned int* chunk_sums = (unsigned int*)(w + 17408);        // 4 KB
    unsigned int* eq_list    = (unsigned int*)(w + 32768);        // 256 KB
    unsigned int* fbz        = (unsigned int*)(w + 32768 + 262144); // 512 KB
    unsigned int* fbA        = fbz;
    unsigned int* fbB        = fbz + 65536;
    unsigned int* fine       = (unsigned int*)(w + (1u << 20));   // 4 MB (wbits=20)

    hipMemsetAsync(w, 0, 22528, stream);                          // sc+sampA+sampB+chunk_sums
    hipMemsetAsync(fine, 0, (size_t)4u << wbits, stream);

    int sgrid = (int)((NS + 255u) / 256u);
    sampleA_kernel<<<sgrid, 256, 0, stream>>>(x, N, sstride, NS, sampA);
    scanA_kernel<<<1, 256, 0, stream>>>(sampA, sc, ks);
    sampleB_kernel<<<sgrid, 256, 0, stream>>>(x, N, sstride, NS, sampB, sc);
    scanB_kernel<<<1, 256, 0, stream>>>(sampB, sc, wbits);

    main_kernel<<<2048, 256, 0, stream>>>(x, n4, N, fine, fbz, sc, wbits);
    chunksum_kernel<<<nchunk, 256, 0, stream>>>(fine, chunk_sums);
    final_kernel<<<1, 256, 0, stream>>>(fine, chunk_sums, sc, k, nchunk);

    fb_hist_kernel<<<1024, 256, 0, stream>>>(x, n4, N, fbA, sc, 0);
    fb_scan_kernel<<<1, 256, 0, stream>>>(fbA, sc, 0, k);
    fb_hist_kernel<<<1024, 256, 0, stream>>>(x, n4, N, fbB, sc, 1);
    fb_scan_kernel<<<1, 256, 0, stream>>>(fbB, sc, 1, k);

    scatter_kernel<<<2048, 256, 0, stream>>>(x, n4, N, out, sc, eq_list, EQ_CAP);
    eqfix_kernel<<<1, 256, 0, stream>>>(out, sc, eq_list, EQ_CAP);
}

// Round 4
// 361.790 us; speedup vs baseline: 2.9921x; 1.0429x over previous
//
#include <hip/hip_runtime.h>
#include <stdint.h>

// Top-k (k=10% of N) by value over flat fp32; scatter values back, zeros
// elsewhere. One full selection read pass + one compare/scatter pass.
//   stage 1: coalesced 64K-element sample (values STORED to ws), two-level
//            scan of the sample only -> window center estimate (+-2^10 codes)
//   stage 2: full pass: count u>window exactly + exact per-u32-value hist
//            inside a 2^20-wide window (4 MB ws)
//   stage 3: chunksum + single-block scan -> exact threshold t_u + tie count
//   fallback: exact 16+16-bit radix (2 extra passes) if window missed
//   stage 4: dense compare/scatter; stable tie-fix (smallest indices win).
// Lessons: R2 - no returning same-address cross-block atomics (319us stall);
//          R3 - no strided sampling (64K isolated cachelines = 2x90us).

#define EQ_CAP 65536

#define SC_WLO   0
#define SC_ABOVE 1
#define SC_TU    2
#define SC_NEED  3
#define SC_EQN   4
#define SC_OK    5
#define SC_FBHI  6
#define SC_FBKR  7
#define SC_SB    8
#define SC_SKR   9

__device__ __forceinline__ unsigned int f2u(float x) {
    unsigned int b = __float_as_uint(x);
    return (b & 0x80000000u) ? ~b : (b | 0x80000000u);
}
__device__ __forceinline__ float u2f(unsigned int u) {
    return __uint_as_float((u & 0x80000000u) ? (u & 0x7FFFFFFFu) : ~u);
}

__device__ __forceinline__ unsigned int block_exscan256(unsigned int v,
                                                        unsigned int* lds,
                                                        int tid)
{
    lds[tid] = v;
    __syncthreads();
    for (int off = 1; off < 256; off <<= 1) {
        unsigned int t = (tid >= off) ? lds[tid - off] : 0u;
        __syncthreads();
        lds[tid] += t;
        __syncthreads();
    }
    return lds[tid] - v;
}

// ---- stage 1a: coalesced sample; store u32s; coarse 2048-bin hist ----
__global__ void __launch_bounds__(256)
sample_kernel(const float* __restrict__ x, long long N,
              unsigned int* __restrict__ samp,       // 65536 u32
              unsigned int* __restrict__ histA)      // 2048 bins (pre-zeroed)
{
    __shared__ unsigned int lh[2048];
    int tid = threadIdx.x;
    for (int i = tid; i < 2048; i += 256) lh[i] = 0u;
    __syncthreads();
    long long cstride = N / 256;                      // block chunk stride
    long long idx = (long long)blockIdx.x * cstride + tid;
    if (idx >= N) idx = N - 1;
    unsigned int u = f2u(x[idx]);
    samp[blockIdx.x * 256 + tid] = u;
    atomicAdd(&lh[u >> 21], 1u);
    __syncthreads();
    for (int i = tid; i < 2048; i += 256) {
        unsigned int c = lh[i];
        if (c) atomicAdd(&histA[i], c);               // non-returning
    }
}

// ---- stage 1b: coarse scan -> bin B + remaining sample rank ----
__global__ void __launch_bounds__(256)
scanA_kernel(const unsigned int* __restrict__ histA,
             unsigned int* __restrict__ sc, unsigned int ks)
{
    __shared__ unsigned int lds[256];
    int tid = threadIdx.x;
    unsigned int loc[8]; unsigned int part = 0u;
    for (int j = 0; j < 8; ++j) {
        unsigned int v = histA[2047 - (tid * 8 + j)];
        loc[j] = v; part += v;
    }
    unsigned int cum = block_exscan256(part, lds, tid);
    for (int j = 0; j < 8; ++j) {
        int bin = 2047 - (tid * 8 + j);
        unsigned int c = loc[j];
        if (cum < ks && cum + c >= ks) { sc[SC_SB] = (unsigned int)bin; sc[SC_SKR] = ks - cum; }
        cum += c;
    }
}

// ---- stage 1c: single block refines using STORED samples (L2-resident) ----
__global__ void __launch_bounds__(256)
sampleB_kernel(const unsigned int* __restrict__ samp,
               unsigned int* __restrict__ sc, unsigned int wbits)
{
    __shared__ unsigned int lh[2048];
    __shared__ unsigned int lds[256];
    int tid = threadIdx.x;
    for (int i = tid; i < 2048; i += 256) lh[i] = 0u;
    __syncthreads();
    unsigned int B = sc[SC_SB];
    unsigned int krem = sc[SC_SKR];
    for (int i = tid; i < 65536; i += 256) {
        unsigned int u = samp[i];
        if ((u >> 21) == B) atomicAdd(&lh[(u >> 10) & 2047u], 1u);
    }
    __syncthreads();
    unsigned int loc[8]; unsigned int part = 0u;
    for (int j = 0; j < 8; ++j) {
        unsigned int v = lh[2047 - (tid * 8 + j)];
        loc[j] = v; part += v;
    }
    unsigned int cum = block_exscan256(part, lds, tid);
    for (int j = 0; j < 8; ++j) {
        int bin = 2047 - (tid * 8 + j);
        unsigned int c = loc[j];
        if (cum < krem && cum + c >= krem) {
            unsigned int uhat = (B << 21) | ((unsigned int)bin << 10) | (1u << 9);
            unsigned int wsize = 1u << wbits;
            unsigned int half = wsize >> 1;
            unsigned int wlo = (uhat > half) ? (uhat - half) : 0u;
            unsigned int wlomax = (unsigned int)(0u - wsize);
            if (wlo > wlomax) wlo = wlomax;
            sc[SC_WLO] = wlo;
        }
        cum += c;
    }
}

// ---------------- stage 2: main full selection pass ----------------
__global__ void __launch_bounds__(256)
main_kernel(const float* __restrict__ x, int n4, long long N,
            unsigned int* __restrict__ fine,
            unsigned int* __restrict__ fbz,   // 131072 u32 to zero (fbA|fbB)
            unsigned int* __restrict__ sc, unsigned int wbits)
{
    __shared__ unsigned int wsum[4];
    int tid = threadIdx.x;
    int g = blockIdx.x * blockDim.x + tid;
    if (g < 131072) fbz[g] = 0u;
    unsigned int wlo = sc[SC_WLO];
    unsigned int whiM1 = wlo + (1u << wbits) - 1u;
    const float4* x4 = (const float4*)x;
    int stride = gridDim.x * blockDim.x;
    unsigned int above = 0u;
    for (int i = g; i < n4; i += stride) {
        float4 v = x4[i];
        unsigned int u;
        u = f2u(v.x); if (u > whiM1) ++above; else if (u >= wlo) atomicAdd(&fine[u - wlo], 1u);
        u = f2u(v.y); if (u > whiM1) ++above; else if (u >= wlo) atomicAdd(&fine[u - wlo], 1u);
        u = f2u(v.z); if (u > whiM1) ++above; else if (u >= wlo) atomicAdd(&fine[u - wlo], 1u);
        u = f2u(v.w); if (u > whiM1) ++above; else if (u >= wlo) atomicAdd(&fine[u - wlo], 1u);
    }
    long long t0 = (long long)n4 * 4;
    if (blockIdx.x == 0 && tid < (int)(N - t0)) {
        unsigned int u = f2u(x[t0 + tid]);
        if (u > whiM1) ++above; else if (u >= wlo) atomicAdd(&fine[u - wlo], 1u);
    }
    for (int o = 32; o; o >>= 1) above += __shfl_down(above, o, 64);
    if ((tid & 63) == 0) wsum[tid >> 6] = above;
    __syncthreads();
    if (tid == 0) {
        unsigned int s = wsum[0] + wsum[1] + wsum[2] + wsum[3];
        if (s) atomicAdd(&sc[SC_ABOVE], s);   // non-returning, 1 per block
    }
}

// ---------------- stage 3: chunksum + final scan ----------------
__global__ void __launch_bounds__(256)
chunksum_kernel(const unsigned int* __restrict__ fine,
                unsigned int* __restrict__ chunk_sums)
{
    __shared__ unsigned int p[256];
    int tid = threadIdx.x;
    const unsigned int* base = fine + (size_t)blockIdx.x * 1024;
    unsigned int s = 0u;
    for (int i = tid; i < 1024; i += 256) s += base[i];
    p[tid] = s;
    __syncthreads();
    for (int o = 128; o; o >>= 1) { if (tid < o) p[tid] += p[tid + o]; __syncthreads(); }
    if (tid == 0) chunk_sums[blockIdx.x] = p[0];
}

__global__ void __launch_bounds__(256)
final_kernel(const unsigned int* __restrict__ fine,
             const unsigned int* __restrict__ chunk_sums,
             unsigned int* __restrict__ sc, unsigned int k, int nchunk)
{
    __shared__ unsigned int lds[256];
    __shared__ unsigned int sh[3];
    __shared__ unsigned int s_total;
    int tid = threadIdx.x;
    unsigned int above = sc[SC_ABOVE];
    int seg = nchunk >> 8;
    unsigned int part = 0u;
    for (int j = 0; j < seg; ++j) part += chunk_sums[nchunk - 1 - (tid * seg + j)];
    unsigned int ex = block_exscan256(part, lds, tid);
    if (tid == 255) s_total = ex + part;
    __syncthreads();
    unsigned int total = s_total;
    unsigned int valid = (above < k) && ((k - above) <= total);
    if (tid == 0) sc[SC_OK] = valid;
    if (!valid) return;
    unsigned int krem = k - above;
    unsigned int cum = ex;
    for (int j = 0; j < seg; ++j) {
        int c = nchunk - 1 - (tid * seg + j);
        unsigned int cc = chunk_sums[c];
        if (cum < krem && cum + cc >= krem) { sh[0] = (unsigned int)c; sh[1] = krem - cum; }
        cum += cc;
    }
    __syncthreads();
    unsigned int C = sh[0], krem2 = sh[1];
    unsigned int loc[4]; unsigned int p2 = 0u;
    for (int j = 0; j < 4; ++j) {
        unsigned int v = fine[(size_t)C * 1024 + (1023 - (tid * 4 + j))];
        loc[j] = v; p2 += v;
    }
    __syncthreads();
    unsigned int ex2 = block_exscan256(p2, lds, tid);
    unsigned int cum2 = ex2;
    for (int j = 0; j < 4; ++j) {
        int bin = 1023 - (tid * 4 + j);
        unsigned int cc = loc[j];
        if (cum2 < krem2 && cum2 + cc >= krem2) {
            sc[SC_TU] = sc[SC_WLO] + C * 1024u + (unsigned int)bin;
            sc[SC_NEED] = krem2 - cum2;
        }
        cum2 += cc;
    }
}

// ---------------- exact fallback (early-exit when SC_OK) ----------------
__global__ void __launch_bounds__(256)
fb_hist_kernel(const float* __restrict__ x, int n4, long long N,
               unsigned int* __restrict__ hist,
               const unsigned int* __restrict__ sc, int lowpass)
{
    if (sc[SC_OK]) return;
    unsigned int pref = lowpass ? sc[SC_FBHI] : 0u;
    const float4* x4 = (const float4*)x;
    int stride = gridDim.x * blockDim.x;
    for (int i = blockIdx.x * blockDim.x + threadIdx.x; i < n4; i += stride) {
        float4 v = x4[i];
        unsigned int u;
        #define FB_ONE(c) u = f2u(c); \
            if (!lowpass) atomicAdd(&hist[u >> 16], 1u); \
            else if ((u >> 16) == pref) atomicAdd(&hist[u & 0xFFFFu], 1u);
        FB_ONE(v.x) FB_ONE(v.y) FB_ONE(v.z) FB_ONE(v.w)
        #undef FB_ONE
    }
    long long t0 = (long long)n4 * 4;
    if (blockIdx.x == 0 && threadIdx.x < (int)(N - t0)) {
        unsigned int u = f2u(x[t0 + threadIdx.x]);
        if (!lowpass) atomicAdd(&hist[u >> 16], 1u);
        else if ((u >> 16) == pref) atomicAdd(&hist[u & 0xFFFFu], 1u);
    }
}

__global__ void __launch_bounds__(256)
fb_scan_kernel(const unsigned int* __restrict__ hist,
               unsigned int* __restrict__ sc, int lowpass, unsigned int k)
{
    if (sc[SC_OK]) return;
    __shared__ unsigned int lds[256];
    int tid = threadIdx.x;
    unsigned int krem = lowpass ? sc[SC_FBKR] : k;
    unsigned int part = 0u;
    for (int j = 0; j < 256; ++j) part += hist[65535 - (tid * 256 + j)];
    unsigned int ex = block_exscan256(part, lds, tid);
    unsigned int cum = ex;
    for (int j = 0; j < 256; ++j) {
        int bin = 65535 - (tid * 256 + j);
        unsigned int cc = hist[bin];
        if (cum < krem && cum + cc >= krem) {
            if (!lowpass) { sc[SC_FBHI] = (unsigned int)bin; sc[SC_FBKR] = krem - cum; }
            else { sc[SC_TU] = (sc[SC_FBHI] << 16) | (unsigned int)bin; sc[SC_NEED] = krem - cum; }
        }
        cum += cc;
    }
}

// ---------------- stage 4: scatter ----------------
__global__ void __launch_bounds__(256)
scatter_kernel(const float* __restrict__ x, int n4, long long N,
               float* __restrict__ out, unsigned int* __restrict__ sc,
               unsigned int* __restrict__ eq_list, int cap)
{
    int tid = threadIdx.x;
    unsigned int tu = sc[SC_TU];
    const float4* x4 = (const float4*)x;
    float4* o4 = (float4*)out;
    int stride = gridDim.x * blockDim.x;
    for (int i = blockIdx.x * blockDim.x + tid; i < n4; i += stride) {
        float4 v = x4[i];
        unsigned int u0 = f2u(v.x), u1 = f2u(v.y), u2 = f2u(v.z), u3 = f2u(v.w);
        float4 o;
        o.x = (u0 > tu) ? v.x : 0.0f;
        o.y = (u1 > tu) ? v.y : 0.0f;
        o.z = (u2 > tu) ? v.z : 0.0f;
        o.w = (u3 > tu) ? v.w : 0.0f;
        if (u0 == tu || u1 == tu || u2 == tu || u3 == tu) {   // ~a few per launch
            unsigned int b = (unsigned int)i * 4u;
            if (u0 == tu) { unsigned int p = atomicAdd(&sc[SC_EQN], 1u); if (p < (unsigned int)cap) eq_list[p] = b + 0u; }
            if (u1 == tu) { unsigned int p = atomicAdd(&sc[SC_EQN], 1u); if (p < (unsigned int)cap) eq_list[p] = b + 1u; }
            if (u2 == tu) { unsigned int p = atomicAdd(&sc[SC_EQN], 1u); if (p < (unsigned int)cap) eq_list[p] = b + 2u; }
            if (u3 == tu) { unsigned int p = atomicAdd(&sc[SC_EQN], 1u); if (p < (unsigned int)cap) eq_list[p] = b + 3u; }
        }
        o4[i] = o;
    }
    long long t0 = (long long)n4 * 4;
    if (blockIdx.x == 0 && tid < (int)(N - t0)) {
        long long idx = t0 + tid;
        float v = x[idx];
        unsigned int u = f2u(v);
        out[idx] = (u > tu) ? v : 0.0f;
        if (u == tu) { unsigned int p = atomicAdd(&sc[SC_EQN], 1u); if (p < (unsigned int)cap) eq_list[p] = (unsigned int)idx; }
    }
}

// stable tie-break: among ==t_u elements, the SC_NEED smallest indices win
__global__ void __launch_bounds__(256)
eqfix_kernel(float* __restrict__ out, const unsigned int* __restrict__ sc,
             const unsigned int* __restrict__ eq_list, int cap)
{
    unsigned int m = sc[SC_EQN]; if (m > (unsigned int)cap) m = (unsigned int)cap;
    unsigned int need = sc[SC_NEED];
    unsigned int tu = sc[SC_TU];
    float f = u2f(tu);
    for (unsigned int j = threadIdx.x; j < m; j += blockDim.x) {
        unsigned int idx = eq_list[j];
        unsigned int cnt = 0u;
        for (unsigned int l = 0; l < m; ++l) cnt += (eq_list[l] < idx) ? 1u : 0u;
        if (cnt < need) out[idx] = f;
    }
}

extern "C" void kernel_launch(void* const* d_in, const int* in_sizes, int n_in,
                              void* d_out, int out_size, void* d_ws, size_t ws_size,
                              hipStream_t stream) {
    const float* x = (const float*)d_in[0];
    float* out = (float*)d_out;
    long long N = (long long)in_sizes[0];
    int n4 = (int)(N >> 2);
    unsigned int k = (unsigned int)((double)N * 0.1);
    if (k == 0u) k = 1u;

    unsigned int NS = 65536u;
    unsigned int ks = (unsigned int)((double)NS * (double)k / (double)N);
    if (ks < 1u) ks = 1u; if (ks > NS) ks = NS;

    unsigned int wbits = 20;
    if (ws_size < ((size_t)2u << 20) + ((size_t)4u << 20)) wbits = 18;
    int nchunk = 1 << (wbits - 10);

    uint8_t* w = (uint8_t*)d_ws;
    unsigned int* sc         = (unsigned int*)w;                    // 1 KB
    unsigned int* histA      = (unsigned int*)(w + 1024);           // 8 KB
    unsigned int* chunk_sums = (unsigned int*)(w + 9216);           // 4 KB
    unsigned int* samp       = (unsigned int*)(w + 32768);          // 256 KB
    unsigned int* eq_list    = (unsigned int*)(w + 294912);         // 256 KB
    unsigned int* fbz        = (unsigned int*)(w + 557056);         // 512 KB
    unsigned int* fbA        = fbz;
    unsigned int* fbB        = fbz + 65536;
    unsigned int* fine       = (unsigned int*)(w + ((size_t)2u << 20)); // 4 MB

    hipMemsetAsync(w, 0, 16384, stream);                 // sc + histA + chunk_sums
    hipMemsetAsync(fine, 0, (size_t)4u << wbits, stream);

    sample_kernel<<<256, 256, 0, stream>>>(x, N, samp, histA);
    scanA_kernel<<<1, 256, 0, stream>>>(histA, sc, ks);
    sampleB_kernel<<<1, 256, 0, stream>>>(samp, sc, wbits);

    main_kernel<<<2048, 256, 0, stream>>>(x, n4, N, fine, fbz, sc, wbits);
    chunksum_kernel<<<nchunk, 256, 0, stream>>>(fine, chunk_sums);
    final_kernel<<<1, 256, 0, stream>>>(fine, chunk_sums, sc, k, nchunk);

    fb_hist_kernel<<<1024, 256, 0, stream>>>(x, n4, N, fbA, sc, 0);
    fb_scan_kernel<<<1, 256, 0, stream>>>(fbA, sc, 0, k);
    fb_hist_kernel<<<1024, 256, 0, stream>>>(x, n4, N, fbB, sc, 1);
    fb_scan_kernel<<<1, 256, 0, stream>>>(fbB, sc, 1, k);

    scatter_kernel<<<2048, 256, 0, stream>>>(x, n4, N, out, sc, eq_list, EQ_CAP);
    eqfix_kernel<<<1, 256, 0, stream>>>(out, sc, eq_list, EQ_CAP);
}